// Round 7
// baseline (864.193 us; speedup 1.0000x reference)
//
#include <hip/hip_runtime.h>

#define DD 64          // node embedding dim
#define RR 8           // num relations
#define KA 576         // (RR+1)*DD : agg rows 0..7 + x as "relation 8"
#define NT 18          // K steps = KA/32
#define NPART 8        // dst partitions ~ XCDs (blockIdx%8 round-robin)
#define ECH 2048       // edges per slice-block in partitioned kernels

typedef short bf16x8 __attribute__((ext_vector_type(8)));   // 8 bf16
typedef float f32x4  __attribute__((ext_vector_type(4)));

__device__ __forceinline__ float bf2f(unsigned short u) {
    union { unsigned u; float f; } c; c.u = ((unsigned)u) << 16; return c.f;
}
__device__ __forceinline__ unsigned short f2bf(float f) {
    union { float f; unsigned u; } c; c.f = f;
    unsigned u = c.u;
    u += 0x7FFF + ((u >> 16) & 1);      // round-to-nearest-even
    return (unsigned short)(u >> 16);
}

// ---------------------------------------------------------------------------
// x -> bf16 rows; row N is an all-zero pad row (targets of dummy pad edges).
// ---------------------------------------------------------------------------
__global__ void k_xcast(const float* __restrict__ x, unsigned short* __restrict__ xb,
                        int N)
{
    int i = blockIdx.x * 256 + threadIdx.x;              // quad index
    int total = (N + 1) * (DD / 4);
    if (i >= total) return;
    ushort4 o;
    if (i < N * (DD / 4)) {
        float4 f = ((const float4*)x)[i];
        o = make_ushort4(f2bf(f.x), f2bf(f.y), f2bf(f.z), f2bf(f.w));
    } else {
        o = make_ushort4(0, 0, 0, 0);
    }
    ((ushort4*)xb)[i] = o;
}

// ---------------------------------------------------------------------------
// Partitioned count: partition p (= blockIdx%8 -> XCD p) owns dst range
// [N*p/8, N*(p+1)/8). cnt cell = dst*RR + rel.
// ---------------------------------------------------------------------------
__global__ __launch_bounds__(256) void k_count_part(
    const int* __restrict__ ei, const int* __restrict__ et,
    int* __restrict__ cnt, int E, int N)
{
    const int p   = blockIdx.x & (NPART - 1);
    const int sb  = blockIdx.x / NPART;
    const int dlo = (int)((long long)N * p / NPART);
    const int dhi = (int)((long long)N * (p + 1) / NPART);
    const int e0  = sb * ECH;
    const int e1  = min(E, e0 + ECH);
    for (int e = e0 + threadIdx.x; e < e1; e += 256) {
        int dst = ei[E + e];
        if (dst >= dlo && dst < dhi)
            atomicAdd(&cnt[(size_t)dst * RR + et[e]], 1);
    }
}

// ---------------------------------------------------------------------------
// Per-dst bucket allocation, padded to a multiple of 8 edges. Pad entries
// (src=N -> zero row, rel=0) are written here so the gather loop is an
// unconditional 8-wide pipeline.
// ---------------------------------------------------------------------------
__global__ __launch_bounds__(256) void k_alloc(
    const int* __restrict__ cnt, int* __restrict__ startv,
    int* __restrict__ headv, int* __restrict__ counter,
    int* __restrict__ sorted, int N)
{
    __shared__ int sdata[256];
    __shared__ int sbase;
    const int tid = threadIdx.x;
    const int n = blockIdx.x * 256 + tid;

    int deg = 0, deg8 = 0;
    if (n < N) {
        const int4* c4 = (const int4*)(cnt + (size_t)n * RR);
        int4 a = c4[0], b = c4[1];
        deg  = a.x + a.y + a.z + a.w + b.x + b.y + b.z + b.w;
        deg8 = (deg + 7) & ~7;
    }
    sdata[tid] = deg8;
    __syncthreads();
    int v = deg8;
    #pragma unroll
    for (int off = 1; off < 256; off <<= 1) {
        int t = (tid >= off) ? sdata[tid - off] : 0;
        __syncthreads();
        v += t;
        sdata[tid] = v;
        __syncthreads();
    }
    if (tid == 255) sbase = atomicAdd(counter, v);
    __syncthreads();
    if (n < N) {
        int st = sbase + v - deg8;
        startv[n] = st;
        headv[n]  = st;
        for (int j = deg; j < deg8; ++j) sorted[st + j] = N;   // pad -> zero row
    }
}

// ---------------------------------------------------------------------------
// Partitioned bucket scatter: sorted[pos] = src | (rel << 24).
// ---------------------------------------------------------------------------
__global__ __launch_bounds__(256) void k_bucket_part(
    const int* __restrict__ ei, const int* __restrict__ et,
    int* __restrict__ headv, int* __restrict__ sorted, int E, int N)
{
    const int p   = blockIdx.x & (NPART - 1);
    const int sb  = blockIdx.x / NPART;
    const int dlo = (int)((long long)N * p / NPART);
    const int dhi = (int)((long long)N * (p + 1) / NPART);
    const int e0  = sb * ECH;
    const int e1  = min(E, e0 + ECH);
    for (int e = e0 + threadIdx.x; e < e1; e += 256) {
        int dst = ei[E + e];
        if (dst >= dlo && dst < dhi) {
            int pos = atomicAdd(&headv[dst], 1);
            sorted[pos] = ei[e] | (et[e] << 24);
        }
    }
}

// ---------------------------------------------------------------------------
// Pack Wcat = [W_rel(8) ; W_root] into MFMA-B fragment order, bf16 hi + lo.
// ---------------------------------------------------------------------------
__global__ void k_packW(const float* __restrict__ Wrel, const float* __restrict__ Wroot,
                        unsigned short* __restrict__ Bh, unsigned short* __restrict__ Bl)
{
    int idx = blockIdx.x * 256 + threadIdx.x;
    if (idx >= NT * 4 * 64 * 8) return;
    int i    = idx & 7;
    int lane = (idx >> 3) & 63;
    int f    = (idx >> 9) & 3;
    int t    = idx >> 11;
    int k = t * 32 + (lane >> 4) * 8 + i;
    int d = f * 16 + (lane & 15);
    int r = k >> 6, kk = k & 63;
    float w = (r < RR) ? Wrel[((size_t)r * DD + kk) * DD + d]
                       : Wroot[(size_t)kk * DD + d];
    unsigned short h = f2bf(w);
    Bh[idx] = h;
    Bl[idx] = f2bf(w - bf2f(h));
}

// ---------------------------------------------------------------------------
// One wave per dst. Padded flat edge stream (multiple of 8): per 8 edges,
// 8 readlane -> scalar (src,rel), 8 independent bf16 gathers in flight,
// routing via non-returning LDS ds_add_f32 (atomicAdd on shared) -- no
// per-edge selects, ~3 VALU/edge. Normalization once per dst in epilogue.
// ---------------------------------------------------------------------------
__global__ __launch_bounds__(256) void k_aggregate(
    const unsigned short* __restrict__ xb, const int* __restrict__ sorted,
    const int* __restrict__ startv, const int* __restrict__ cnt,
    unsigned short* __restrict__ agg, int c0, int c1)
{
    __shared__ float acc[4][RR][64];
    const int wv   = threadIdx.x >> 6;
    const int lane = threadIdx.x & 63;
    const int dst  = c0 + blockIdx.x * 4 + wv;
    if (dst >= c1) return;

    // zero this wave's accumulator block (own region; wave-ordered LDS)
    #pragma unroll
    for (int r = 0; r < RR; ++r) acc[wv][r][lane] = 0.f;

    const int4* c4 = (const int4*)(cnt + (size_t)dst * RR);
    const int4 ca = c4[0], cb = c4[1];
    int deg  = ca.x + ca.y + ca.z + ca.w + cb.x + cb.y + cb.z + cb.w;
    int deg8 = (deg + 7) & ~7;
    const int s0  = __builtin_amdgcn_readfirstlane(startv[dst]);
    const int end = s0 + __builtin_amdgcn_readfirstlane(deg8);

    int wbase = s0;
    int vidx  = sorted[wbase + lane];
    int e = s0;
    while (e < end) {
        if (e - wbase >= 64) {                 // slide 64-edge index window
            wbase = e;
            vidx  = sorted[wbase + lane];
        }
        const int k    = e - wbase;            // uniform, multiple of 8
        const int take = min(end - e, 64 - k); // multiple of 8
        for (int i = 0; i < take; i += 8) {
            unsigned p0 = (unsigned)__builtin_amdgcn_readlane(vidx, k + i + 0);
            unsigned p1 = (unsigned)__builtin_amdgcn_readlane(vidx, k + i + 1);
            unsigned p2 = (unsigned)__builtin_amdgcn_readlane(vidx, k + i + 2);
            unsigned p3 = (unsigned)__builtin_amdgcn_readlane(vidx, k + i + 3);
            unsigned p4 = (unsigned)__builtin_amdgcn_readlane(vidx, k + i + 4);
            unsigned p5 = (unsigned)__builtin_amdgcn_readlane(vidx, k + i + 5);
            unsigned p6 = (unsigned)__builtin_amdgcn_readlane(vidx, k + i + 6);
            unsigned p7 = (unsigned)__builtin_amdgcn_readlane(vidx, k + i + 7);
            float v0 = bf2f(xb[(size_t)(p0 & 0xFFFFFFu) * DD + lane]);
            float v1 = bf2f(xb[(size_t)(p1 & 0xFFFFFFu) * DD + lane]);
            float v2 = bf2f(xb[(size_t)(p2 & 0xFFFFFFu) * DD + lane]);
            float v3 = bf2f(xb[(size_t)(p3 & 0xFFFFFFu) * DD + lane]);
            float v4 = bf2f(xb[(size_t)(p4 & 0xFFFFFFu) * DD + lane]);
            float v5 = bf2f(xb[(size_t)(p5 & 0xFFFFFFu) * DD + lane]);
            float v6 = bf2f(xb[(size_t)(p6 & 0xFFFFFFu) * DD + lane]);
            float v7 = bf2f(xb[(size_t)(p7 & 0xFFFFFFu) * DD + lane]);
            atomicAdd(&acc[wv][p0 >> 24][lane], v0);   // ds_add_f32, no return
            atomicAdd(&acc[wv][p1 >> 24][lane], v1);
            atomicAdd(&acc[wv][p2 >> 24][lane], v2);
            atomicAdd(&acc[wv][p3 >> 24][lane], v3);
            atomicAdd(&acc[wv][p4 >> 24][lane], v4);
            atomicAdd(&acc[wv][p5 >> 24][lane], v5);
            atomicAdd(&acc[wv][p6 >> 24][lane], v6);
            atomicAdd(&acc[wv][p7 >> 24][lane], v7);
        }
        e += take;
    }

    __builtin_amdgcn_s_waitcnt(0);   // drain this wave's ds_adds (lgkmcnt)

    unsigned short* ao = agg + (size_t)(dst - c0) * KA + lane;
    ao[0*DD] = f2bf(acc[wv][0][lane] * (1.f / fmaxf((float)ca.x, 1.f)));
    ao[1*DD] = f2bf(acc[wv][1][lane] * (1.f / fmaxf((float)ca.y, 1.f)));
    ao[2*DD] = f2bf(acc[wv][2][lane] * (1.f / fmaxf((float)ca.z, 1.f)));
    ao[3*DD] = f2bf(acc[wv][3][lane] * (1.f / fmaxf((float)ca.w, 1.f)));
    ao[4*DD] = f2bf(acc[wv][4][lane] * (1.f / fmaxf((float)cb.x, 1.f)));
    ao[5*DD] = f2bf(acc[wv][5][lane] * (1.f / fmaxf((float)cb.y, 1.f)));
    ao[6*DD] = f2bf(acc[wv][6][lane] * (1.f / fmaxf((float)cb.z, 1.f)));
    ao[7*DD] = f2bf(acc[wv][7][lane] * (1.f / fmaxf((float)cb.w, 1.f)));
    ao[8*DD] = xb[(size_t)dst * DD + lane];       // x row, already bf16
}

// ---------------------------------------------------------------------------
// out[64-node tile] = A(64x576) @ (Bh + Bl)(576x64) + bias   via MFMA bf16.
// ---------------------------------------------------------------------------
__global__ __launch_bounds__(256) void k_transform_mfma(
    const unsigned short* __restrict__ A,
    const unsigned short* __restrict__ Bh,
    const unsigned short* __restrict__ Bl,
    const float* __restrict__ bias,
    float* __restrict__ out, int c0, int c1)
{
    const int nb   = c0 + blockIdx.x * 64;
    const int wv   = threadIdx.x >> 6;
    const int lane = threadIdx.x & 63;
    const int rlo  = lane & 15;        // A row within 16 / D col within 16
    const int kg   = lane >> 4;        // k-group

    const unsigned short* ap = A + ((size_t)(nb - c0) + wv * 16 + rlo) * KA + kg * 8;

    f32x4 acc0 = {0.f,0.f,0.f,0.f};
    f32x4 acc1 = {0.f,0.f,0.f,0.f};
    f32x4 acc2 = {0.f,0.f,0.f,0.f};
    f32x4 acc3 = {0.f,0.f,0.f,0.f};

    #pragma unroll
    for (int t = 0; t < NT; ++t) {
        bf16x8 a = *(const bf16x8*)(ap + t * 32);
        const unsigned short* bh = Bh + (size_t)t * 2048 + lane * 8;
        const unsigned short* bl = Bl + (size_t)t * 2048 + lane * 8;
        bf16x8 b;
        b = *(const bf16x8*)(bh +    0); acc0 = __builtin_amdgcn_mfma_f32_16x16x32_bf16(a, b, acc0, 0, 0, 0);
        b = *(const bf16x8*)(bh +  512); acc1 = __builtin_amdgcn_mfma_f32_16x16x32_bf16(a, b, acc1, 0, 0, 0);
        b = *(const bf16x8*)(bh + 1024); acc2 = __builtin_amdgcn_mfma_f32_16x16x32_bf16(a, b, acc2, 0, 0, 0);
        b = *(const bf16x8*)(bh + 1536); acc3 = __builtin_amdgcn_mfma_f32_16x16x32_bf16(a, b, acc3, 0, 0, 0);
        b = *(const bf16x8*)(bl +    0); acc0 = __builtin_amdgcn_mfma_f32_16x16x32_bf16(a, b, acc0, 0, 0, 0);
        b = *(const bf16x8*)(bl +  512); acc1 = __builtin_amdgcn_mfma_f32_16x16x32_bf16(a, b, acc1, 0, 0, 0);
        b = *(const bf16x8*)(bl + 1024); acc2 = __builtin_amdgcn_mfma_f32_16x16x32_bf16(a, b, acc2, 0, 0, 0);
        b = *(const bf16x8*)(bl + 1536); acc3 = __builtin_amdgcn_mfma_f32_16x16x32_bf16(a, b, acc3, 0, 0, 0);
    }

    // C/D layout: col = lane&15, row = (lane>>4)*4 + reg
    const float b0 = bias[rlo];
    const float b1 = bias[rlo + 16];
    const float b2 = bias[rlo + 32];
    const float b3 = bias[rlo + 48];
    const int orow = nb + wv * 16 + kg * 4;
    #pragma unroll
    for (int j = 0; j < 4; ++j) {
        int r = orow + j;
        if (r < c1) {
            float* op = out + (size_t)r * DD + rlo;
            op[0]  = acc0[j] + b0;
            op[16] = acc1[j] + b1;
            op[32] = acc2[j] + b2;
            op[48] = acc3[j] + b3;
        }
    }
}

// ---------------------------------------------------------------------------
// echo edge_index / edge_type into d_out tail as float
// ---------------------------------------------------------------------------
__global__ void k_echo(const int* __restrict__ ei, const int* __restrict__ et,
                       float* __restrict__ out_ei, float* __restrict__ out_et,
                       int E)
{
    int i = blockIdx.x * 256 + threadIdx.x;
    if (i < 2 * E) out_ei[i] = (float)ei[i];
    if (i < E)     out_et[i] = (float)et[i];
}

extern "C" void kernel_launch(void* const* d_in, const int* in_sizes, int n_in,
                              void* d_out, int out_size, void* d_ws, size_t ws_size,
                              hipStream_t stream)
{
    const float* x     = (const float*)d_in[0];
    const int*   ei    = (const int*)d_in[1];
    const int*   et    = (const int*)d_in[2];
    const float* Wrel  = (const float*)d_in[3];
    const float* Wroot = (const float*)d_in[4];
    const float* bias  = (const float*)d_in[5];

    const int N = in_sizes[0] / DD;
    const int E = in_sizes[2];
    const int M = N * RR;

    float* out    = (float*)d_out;
    float* out_ei = out + (size_t)N * DD;
    float* out_et = out_ei + (size_t)2 * E;

    auto align = [](size_t v) { return (v + 255) & ~(size_t)255; };

    // workspace layout
    size_t p = 0;
    int* cnt = (int*)((char*)d_ws + p);              p += align((size_t)M * 4);
    int* counter = (int*)((char*)d_ws + p);
    size_t zero_bytes = p + 256;                     p += 256;
    int* startv = (int*)((char*)d_ws + p);           p += align((size_t)N * 4);
    int* headv  = (int*)((char*)d_ws + p);           p += align((size_t)N * 4);
    int* sorted = (int*)((char*)d_ws + p);           p += align(((size_t)E + 7*(size_t)N + 128) * 4);
    unsigned short* xb = (unsigned short*)((char*)d_ws + p); p += align(((size_t)N + 1) * DD * 2);
    unsigned short* Bh = (unsigned short*)((char*)d_ws + p); p += align((size_t)NT*4*64*8*2);
    unsigned short* Bl = (unsigned short*)((char*)d_ws + p); p += align((size_t)NT*4*64*8*2);
    unsigned short* agg = (unsigned short*)((char*)d_ws + p);
    size_t avail = (ws_size > p) ? ws_size - p : 0;

    const size_t per_node = (size_t)KA * 2;          // 1152 B
    int chunk = (int)(((avail / per_node) - 64) & ~(size_t)63);
    if (chunk > N) chunk = (N + 63) & ~(size_t)63;
    if (chunk < 64) chunk = 64;

    hipMemsetAsync(d_ws, 0, zero_bytes, stream);     // cnt + counter

    const int nsb = (E + ECH - 1) / ECH;             // slice-blocks per partition

    k_xcast <<<dim3(((N + 1) * (DD/4) + 255) / 256), 256, 0, stream>>>(x, xb, N);
    k_packW <<<dim3((NT*4*64*8 + 255) / 256), 256, 0, stream>>>(Wrel, Wroot, Bh, Bl);
    k_count_part <<<dim3(nsb * NPART), 256, 0, stream>>>(ei, et, cnt, E, N);
    k_alloc <<<dim3((N + 255) / 256), 256, 0, stream>>>(cnt, startv, headv,
                                                        counter, sorted, N);
    k_bucket_part<<<dim3(nsb * NPART), 256, 0, stream>>>(ei, et, headv, sorted, E, N);

    for (int c0 = 0; c0 < N; c0 += chunk) {
        int c1 = min(N, c0 + chunk);
        int nc = c1 - c0;
        k_aggregate     <<<dim3((nc + 3) / 4),   256, 0, stream>>>(
            xb, sorted, startv, cnt, agg, c0, c1);
        k_transform_mfma<<<dim3((nc + 63) / 64), 256, 0, stream>>>(
            agg, Bh, Bl, bias, out, c0, c1);
    }

    k_echo<<<dim3((2 * E + 255) / 256), 256, 0, stream>>>(ei, et, out_ei, out_et, E);
}

// Round 8
// 281.545 us; speedup vs baseline: 3.0695x; 3.0695x over previous
//
#include <hip/hip_runtime.h>

#define DD 64          // node embedding dim
#define RR 8           // num relations
#define KA 576         // (RR+1)*DD : agg rows 0..7 + x as "relation 8"
#define NT 18          // K steps = KA/32
#define NPART 8        // dst partitions ~ XCDs (blockIdx%8 round-robin)
#define ECH 2048       // edges per slice-block in partitioned kernels

typedef short bf16x8 __attribute__((ext_vector_type(8)));   // 8 bf16
typedef float f32x4  __attribute__((ext_vector_type(4)));

__device__ __forceinline__ float bf2f(unsigned short u) {
    union { unsigned u; float f; } c; c.u = ((unsigned)u) << 16; return c.f;
}
__device__ __forceinline__ unsigned short f2bf(float f) {
    union { float f; unsigned u; } c; c.f = f;
    unsigned u = c.u;
    u += 0x7FFF + ((u >> 16) & 1);      // round-to-nearest-even
    return (unsigned short)(u >> 16);
}

// ---------------------------------------------------------------------------
// x -> bf16 rows; row N is an all-zero pad row (targets of dummy pad edges).
// ---------------------------------------------------------------------------
__global__ void k_xcast(const float* __restrict__ x, unsigned short* __restrict__ xb,
                        int N)
{
    int i = blockIdx.x * 256 + threadIdx.x;              // quad index
    int total = (N + 1) * (DD / 4);
    if (i >= total) return;
    ushort4 o;
    if (i < N * (DD / 4)) {
        float4 f = ((const float4*)x)[i];
        o = make_ushort4(f2bf(f.x), f2bf(f.y), f2bf(f.z), f2bf(f.w));
    } else {
        o = make_ushort4(0, 0, 0, 0);
    }
    ((ushort4*)xb)[i] = o;
}

// ---------------------------------------------------------------------------
// Partitioned count: partition p (= blockIdx%8 -> XCD p) owns dst range
// [N*p/8, N*(p+1)/8). cnt cell = dst*RR + rel.
// ---------------------------------------------------------------------------
__global__ __launch_bounds__(256) void k_count_part(
    const int* __restrict__ ei, const int* __restrict__ et,
    int* __restrict__ cnt, int E, int N)
{
    const int p   = blockIdx.x & (NPART - 1);
    const int sb  = blockIdx.x / NPART;
    const int dlo = (int)((long long)N * p / NPART);
    const int dhi = (int)((long long)N * (p + 1) / NPART);
    const int e0  = sb * ECH;
    const int e1  = min(E, e0 + ECH);
    for (int e = e0 + threadIdx.x; e < e1; e += 256) {
        int dst = ei[E + e];
        if (dst >= dlo && dst < dhi)
            atomicAdd(&cnt[(size_t)dst * RR + et[e]], 1);
    }
}

// ---------------------------------------------------------------------------
// Per-dst bucket allocation (padded to x8) + per-(dst,rel) cell heads, so
// the bucket scatter produces rel-ORDERED runs inside each dst bucket.
// Pad entries (src=N -> zero row) sit after run 7.
// ---------------------------------------------------------------------------
__global__ __launch_bounds__(256) void k_alloc(
    const int* __restrict__ cnt, int* __restrict__ startv,
    int* __restrict__ head2, int* __restrict__ counter,
    int* __restrict__ sorted, int N)
{
    __shared__ int sdata[256];
    __shared__ int sbase;
    const int tid = threadIdx.x;
    const int n = blockIdx.x * 256 + tid;

    int deg = 0, deg8 = 0;
    int c[RR];
    if (n < N) {
        const int4* c4 = (const int4*)(cnt + (size_t)n * RR);
        int4 a = c4[0], b = c4[1];
        c[0]=a.x; c[1]=a.y; c[2]=a.z; c[3]=a.w;
        c[4]=b.x; c[5]=b.y; c[6]=b.z; c[7]=b.w;
        #pragma unroll
        for (int r = 0; r < RR; ++r) deg += c[r];
        deg8 = (deg + 7) & ~7;
    }
    sdata[tid] = deg8;
    __syncthreads();
    int v = deg8;
    #pragma unroll
    for (int off = 1; off < 256; off <<= 1) {
        int t = (tid >= off) ? sdata[tid - off] : 0;
        __syncthreads();
        v += t;
        sdata[tid] = v;
        __syncthreads();
    }
    if (tid == 255) sbase = atomicAdd(counter, v);
    __syncthreads();
    if (n < N) {
        int st = sbase + v - deg8;
        startv[n] = st;
        int h = st;
        #pragma unroll
        for (int r = 0; r < RR; ++r) { head2[(size_t)n * RR + r] = h; h += c[r]; }
        for (int j = deg; j < deg8; ++j) sorted[st + j] = N;   // pad -> zero row
    }
}

// ---------------------------------------------------------------------------
// Partitioned bucket scatter into rel-ordered runs: sorted[pos] = src.
// ---------------------------------------------------------------------------
__global__ __launch_bounds__(256) void k_bucket_part(
    const int* __restrict__ ei, const int* __restrict__ et,
    int* __restrict__ head2, int* __restrict__ sorted, int E, int N)
{
    const int p   = blockIdx.x & (NPART - 1);
    const int sb  = blockIdx.x / NPART;
    const int dlo = (int)((long long)N * p / NPART);
    const int dhi = (int)((long long)N * (p + 1) / NPART);
    const int e0  = sb * ECH;
    const int e1  = min(E, e0 + ECH);
    for (int e = e0 + threadIdx.x; e < e1; e += 256) {
        int dst = ei[E + e];
        if (dst >= dlo && dst < dhi) {
            int pos = atomicAdd(&head2[(size_t)dst * RR + et[e]], 1);
            sorted[pos] = ei[e];
        }
    }
}

// ---------------------------------------------------------------------------
// Pack Wcat = [W_rel(8) ; W_root] into MFMA-B fragment order (bf16 hi only;
// absmax headroom is ~4 orders of magnitude, lo-pass dropped).
// ---------------------------------------------------------------------------
__global__ void k_packW(const float* __restrict__ Wrel, const float* __restrict__ Wroot,
                        unsigned short* __restrict__ Bh)
{
    int idx = blockIdx.x * 256 + threadIdx.x;
    if (idx >= NT * 4 * 64 * 8) return;
    int i    = idx & 7;
    int lane = (idx >> 3) & 63;
    int f    = (idx >> 9) & 3;
    int t    = idx >> 11;
    int k = t * 32 + (lane >> 4) * 8 + i;
    int d = f * 16 + (lane & 15);
    int r = k >> 6, kk = k & 63;
    float w = (r < RR) ? Wrel[((size_t)r * DD + kk) * DD + d]
                       : Wroot[(size_t)kk * DD + d];
    Bh[idx] = f2bf(w);
}

// ---------------------------------------------------------------------------
// One wave per dst. Bucket is rel-ordered + padded to x8: flat 8-wide
// pipelined gather into a SINGLE accumulator; at run boundaries (wave-uniform
// scalars) flush cur*rcp(cnt) to the agg row. ~3 VALU/edge, no routing.
// ---------------------------------------------------------------------------
__global__ __launch_bounds__(256) void k_aggregate(
    const unsigned short* __restrict__ xb, const int* __restrict__ sorted,
    const int* __restrict__ startv, const int* __restrict__ cnt,
    unsigned short* __restrict__ agg, int c0, int c1)
{
    const int wv   = threadIdx.x >> 6;
    const int lane = threadIdx.x & 63;
    const int dst  = c0 + blockIdx.x * 4 + wv;
    if (dst >= c1) return;

    // lane r (r = lane&7) holds cnt[dst*8+r]; scalars extracted via readlane
    const int cv = cnt[(size_t)dst * RR + (lane & 7)];
    int deg = 0;
    #pragma unroll
    for (int r = 0; r < RR; ++r) deg += __builtin_amdgcn_readlane(cv, r);
    const int deg8 = (deg + 7) & ~7;

    const int s0  = __builtin_amdgcn_readfirstlane(startv[dst]);
    const int end = s0 + deg8;

    unsigned short* ao = agg + (size_t)(dst - c0) * KA + lane;

    // run-flush state (wave-uniform)
    int   r      = 0;
    int   c_r    = __builtin_amdgcn_readlane(cv, 0);
    int   next_b = s0 + c_r;
    float cur    = 0.f;

    auto flush = [&]() {
        float inv = __builtin_amdgcn_rcpf(fmaxf((float)c_r, 1.f));
        ao[r * DD] = f2bf(cur * inv);
        cur = 0.f;
        ++r;
        c_r = __builtin_amdgcn_readlane(cv, r & 7);
        next_b += c_r;
    };

    int e = s0;
    int wbase = s0;
    int vidx  = sorted[wbase + lane];
    while (e < end) {
        if (e - wbase >= 64) {                 // slide 64-edge index window
            wbase = e;
            vidx  = sorted[wbase + lane];
        }
        const int k    = e - wbase;            // uniform, multiple of 8
        const int take = min(end - e, 64 - k); // multiple of 8
        for (int i = 0; i < take; i += 8) {
            int q0 = __builtin_amdgcn_readlane(vidx, k + i + 0);
            int q1 = __builtin_amdgcn_readlane(vidx, k + i + 1);
            int q2 = __builtin_amdgcn_readlane(vidx, k + i + 2);
            int q3 = __builtin_amdgcn_readlane(vidx, k + i + 3);
            int q4 = __builtin_amdgcn_readlane(vidx, k + i + 4);
            int q5 = __builtin_amdgcn_readlane(vidx, k + i + 5);
            int q6 = __builtin_amdgcn_readlane(vidx, k + i + 6);
            int q7 = __builtin_amdgcn_readlane(vidx, k + i + 7);
            unsigned short u0 = xb[(size_t)q0 * DD + lane];   // 8 loads in flight
            unsigned short u1 = xb[(size_t)q1 * DD + lane];
            unsigned short u2 = xb[(size_t)q2 * DD + lane];
            unsigned short u3 = xb[(size_t)q3 * DD + lane];
            unsigned short u4 = xb[(size_t)q4 * DD + lane];
            unsigned short u5 = xb[(size_t)q5 * DD + lane];
            unsigned short u6 = xb[(size_t)q6 * DD + lane];
            unsigned short u7 = xb[(size_t)q7 * DD + lane];
            const int base = e + i;
            while (base + 0 == next_b && r < RR) flush();
            cur += bf2f(u0);
            while (base + 1 == next_b && r < RR) flush();
            cur += bf2f(u1);
            while (base + 2 == next_b && r < RR) flush();
            cur += bf2f(u2);
            while (base + 3 == next_b && r < RR) flush();
            cur += bf2f(u3);
            while (base + 4 == next_b && r < RR) flush();
            cur += bf2f(u4);
            while (base + 5 == next_b && r < RR) flush();
            cur += bf2f(u5);
            while (base + 6 == next_b && r < RR) flush();
            cur += bf2f(u6);
            while (base + 7 == next_b && r < RR) flush();
            cur += bf2f(u7);
        }
        e += take;
    }
    while (r < RR) flush();                    // drain (covers empties, deg=0)

    ao[8 * DD] = xb[(size_t)dst * DD + lane];  // x row, already bf16
}

// ---------------------------------------------------------------------------
// out[64-node tile] = A(64x576) @ Bh(576x64) + bias   via MFMA bf16.
// ---------------------------------------------------------------------------
__global__ __launch_bounds__(256) void k_transform_mfma(
    const unsigned short* __restrict__ A,
    const unsigned short* __restrict__ Bh,
    const float* __restrict__ bias,
    float* __restrict__ out, int c0, int c1)
{
    const int nb   = c0 + blockIdx.x * 64;
    const int wv   = threadIdx.x >> 6;
    const int lane = threadIdx.x & 63;
    const int rlo  = lane & 15;        // A row within 16 / D col within 16
    const int kg   = lane >> 4;        // k-group

    const unsigned short* ap = A + ((size_t)(nb - c0) + wv * 16 + rlo) * KA + kg * 8;

    f32x4 acc0 = {0.f,0.f,0.f,0.f};
    f32x4 acc1 = {0.f,0.f,0.f,0.f};
    f32x4 acc2 = {0.f,0.f,0.f,0.f};
    f32x4 acc3 = {0.f,0.f,0.f,0.f};

    #pragma unroll
    for (int t = 0; t < NT; ++t) {
        bf16x8 a = *(const bf16x8*)(ap + t * 32);
        const unsigned short* bh = Bh + (size_t)t * 2048 + lane * 8;
        bf16x8 b;
        b = *(const bf16x8*)(bh +    0); acc0 = __builtin_amdgcn_mfma_f32_16x16x32_bf16(a, b, acc0, 0, 0, 0);
        b = *(const bf16x8*)(bh +  512); acc1 = __builtin_amdgcn_mfma_f32_16x16x32_bf16(a, b, acc1, 0, 0, 0);
        b = *(const bf16x8*)(bh + 1024); acc2 = __builtin_amdgcn_mfma_f32_16x16x32_bf16(a, b, acc2, 0, 0, 0);
        b = *(const bf16x8*)(bh + 1536); acc3 = __builtin_amdgcn_mfma_f32_16x16x32_bf16(a, b, acc3, 0, 0, 0);
    }

    // C/D layout: col = lane&15, row = (lane>>4)*4 + reg
    const float b0 = bias[rlo];
    const float b1 = bias[rlo + 16];
    const float b2 = bias[rlo + 32];
    const float b3 = bias[rlo + 48];
    const int orow = nb + wv * 16 + kg * 4;
    #pragma unroll
    for (int j = 0; j < 4; ++j) {
        int rr = orow + j;
        if (rr < c1) {
            float* op = out + (size_t)rr * DD + rlo;
            op[0]  = acc0[j] + b0;
            op[16] = acc1[j] + b1;
            op[32] = acc2[j] + b2;
            op[48] = acc3[j] + b3;
        }
    }
}

// ---------------------------------------------------------------------------
// echo edge_index / edge_type into d_out tail as float
// ---------------------------------------------------------------------------
__global__ void k_echo(const int* __restrict__ ei, const int* __restrict__ et,
                       float* __restrict__ out_ei, float* __restrict__ out_et,
                       int E)
{
    int i = blockIdx.x * 256 + threadIdx.x;
    if (i < 2 * E) out_ei[i] = (float)ei[i];
    if (i < E)     out_et[i] = (float)et[i];
}

extern "C" void kernel_launch(void* const* d_in, const int* in_sizes, int n_in,
                              void* d_out, int out_size, void* d_ws, size_t ws_size,
                              hipStream_t stream)
{
    const float* x     = (const float*)d_in[0];
    const int*   ei    = (const int*)d_in[1];
    const int*   et    = (const int*)d_in[2];
    const float* Wrel  = (const float*)d_in[3];
    const float* Wroot = (const float*)d_in[4];
    const float* bias  = (const float*)d_in[5];

    const int N = in_sizes[0] / DD;
    const int E = in_sizes[2];
    const int M = N * RR;

    float* out    = (float*)d_out;
    float* out_ei = out + (size_t)N * DD;
    float* out_et = out_ei + (size_t)2 * E;

    auto align = [](size_t v) { return (v + 255) & ~(size_t)255; };

    // workspace layout
    size_t p = 0;
    int* cnt = (int*)((char*)d_ws + p);              p += align((size_t)M * 4);
    int* counter = (int*)((char*)d_ws + p);
    size_t zero_bytes = p + 256;                     p += 256;
    int* startv = (int*)((char*)d_ws + p);           p += align((size_t)N * 4);
    int* head2  = (int*)((char*)d_ws + p);           p += align((size_t)M * 4);
    int* sorted = (int*)((char*)d_ws + p);           p += align(((size_t)E + 7*(size_t)N + 128) * 4);
    unsigned short* xb = (unsigned short*)((char*)d_ws + p); p += align(((size_t)N + 1) * DD * 2);
    unsigned short* Bh = (unsigned short*)((char*)d_ws + p); p += align((size_t)NT*4*64*8*2);
    unsigned short* agg = (unsigned short*)((char*)d_ws + p);
    size_t avail = (ws_size > p) ? ws_size - p : 0;

    const size_t per_node = (size_t)KA * 2;          // 1152 B
    int chunk = (int)(((avail / per_node) - 64) & ~(size_t)63);
    if (chunk > N) chunk = (N + 63) & ~(size_t)63;
    if (chunk < 64) chunk = 64;

    hipMemsetAsync(d_ws, 0, zero_bytes, stream);     // cnt + counter

    const int nsb = (E + ECH - 1) / ECH;             // slice-blocks per partition

    k_xcast <<<dim3(((N + 1) * (DD/4) + 255) / 256), 256, 0, stream>>>(x, xb, N);
    k_packW <<<dim3((NT*4*64*8 + 255) / 256), 256, 0, stream>>>(Wrel, Wroot, Bh);
    k_count_part <<<dim3(nsb * NPART), 256, 0, stream>>>(ei, et, cnt, E, N);
    k_alloc <<<dim3((N + 255) / 256), 256, 0, stream>>>(cnt, startv, head2,
                                                        counter, sorted, N);
    k_bucket_part<<<dim3(nsb * NPART), 256, 0, stream>>>(ei, et, head2, sorted, E, N);

    for (int c0 = 0; c0 < N; c0 += chunk) {
        int c1 = min(N, c0 + chunk);
        int nc = c1 - c0;
        k_aggregate     <<<dim3((nc + 3) / 4),   256, 0, stream>>>(
            xb, sorted, startv, cnt, agg, c0, c1);
        k_transform_mfma<<<dim3((nc + 63) / 64), 256, 0, stream>>>(
            agg, Bh, bias, out, c0, c1);
    }

    k_echo<<<dim3((2 * E + 255) / 256), 256, 0, stream>>>(ei, et, out_ei, out_et, E);
}